// Round 13
// baseline (675.739 us; speedup 1.0000x reference)
//
#include <hip/hip_runtime.h>

// FeedBack LSTM: B=1024, T_in=128, F=3, UNITS=256, out_steps=32.
// R13: TWO-GROUP PIPELINE. R6-R12 converged at 2.7-3.0us/step because the
// exchange RT has nothing to overlap it. Now each block runs TWO independent
// batch groups (A,B) sharing the same AGPR-resident weight slice:
//   per step: acqA -> compA -> pubA -> acqB -> compB -> pubB
// Steady-state skew: peer's pub of X(t-1) lands ~0.6us before our acq X(t)
// -> acquire = one bulk tagged load, first try. No sentinel, no counter;
// per-thread predicated retry w/ s_sleep(4) backstop (rare by construction).
// 32 super-groups x 2 members = 64 blocks; LDS 81KB (1 block/CU);
// A-frags streamed per-kt (no a[8] preload) to fit the 256-reg/lane cap.

#define TIN    128
#define FIN    3
#define OSTEPS 32
#define LASTT  (TIN + OSTEPS - 1)   // t = 0..159; t==159 is head-only

typedef float    f32x4 __attribute__((ext_vector_type(4)));
typedef _Float16 half8 __attribute__((ext_vector_type(8)));
typedef unsigned long long u64;
typedef unsigned int u32;

__device__ __forceinline__ float fast_rcp(float x) { return __builtin_amdgcn_rcpf(x); }
__device__ __forceinline__ float sigm(float x)  { return fast_rcp(1.0f + __expf(-x)); }
__device__ __forceinline__ float tanh_f(float x){ return 1.0f - 2.0f * fast_rcp(__expf(2.0f * x) + 1.0f); }

// Pack Wr [256][1024] fp32 -> fp16 B-frags. Tile T = p*32 + q*8 + w covers
// cols q*256 + p*128 + w*16 + (l&15); k = kt*32 + (l>>4)*8 + j.
// P[(T*8+kt)*512 + l*8 + j] = Wr[k][col]
__global__ __launch_bounds__(512) void pack_wr(const float* __restrict__ Wr,
                                               _Float16* __restrict__ P)
{
    int idx = blockIdx.x * 512 + threadIdx.x;   // 64 blocks -> 32768
    int l   = idx & 63;
    int kt  = (idx >> 6) & 7;
    int T   = idx >> 9;                         // 0..63
    int p = T >> 5, q = (T >> 3) & 3, w = T & 7;
    int col = q * 256 + p * 128 + w * 16 + (l & 15);
    int k0  = kt * 32 + (l >> 4) * 8;
    half8 v;
#pragma unroll
    for (int j = 0; j < 8; ++j) v[j] = (_Float16)Wr[(k0 + j) * 1024 + col];
    *reinterpret_cast<half8*>(P + (size_t)idx * 8) = v;
}

__global__ __launch_bounds__(512, 2) void lstm_pair(
    const float* __restrict__ x_in,   // [1024][128][3]
    const float* __restrict__ Wk,     // [3][1024]
    const float* __restrict__ bias,   // [1024]
    const float* __restrict__ Wd,     // [256][3]
    const float* __restrict__ bd,     // [3]
    const _Float16* __restrict__ WrP, // packed B-frags
    u32*   __restrict__ hexT,         // [2 par][64 grp][2 mem][2048] tagged words
    float* __restrict__ out)          // [1024][32][3]
{
    __shared__ float                xs[2][16 * TIN * FIN];   // 48 KB inputs
    __shared__ alignas(16) _Float16 hf[2][2][4096];          // [grp][par], 32 KB
    __shared__ float                pb[2][16][4];            // predictions

    const int tid  = threadIdx.x;
    const int w    = tid >> 6;            // wave 0..7
    const int l    = tid & 63;
    const int n    = l & 15;
    const int row0 = (l >> 4) * 4;        // MFMA C rows for this lane
    const int bid  = blockIdx.x;          // 0..63
    const int p    = (bid >> 3) & 1;      // member: units [p*128,(p+1)*128)
    const int pp   = 1 - p;
    const int sg   = (bid & 7) + 8 * (bid >> 4);   // super-group 0..31 (pair same XCD)
    const int g0   = sg * 2;              // group A
    const int g1   = sg * 2 + 1;          // group B

    // ---- prologue: stage x for both groups ----
    for (int G = 0; G < 2; ++G) {
        const float* xsrc = x_in + (size_t)(sg * 2 + G) * 16 * TIN * FIN;
        for (int i = tid; i < 16 * TIN * FIN; i += 512) xs[G][i] = xsrc[i];
    }

    half8 bfr[4][8];                      // weight slice (AGPR resident, shared A/B)
#pragma unroll
    for (int q = 0; q < 4; ++q)
#pragma unroll
        for (int kt = 0; kt < 8; ++kt)
            bfr[q][kt] = *reinterpret_cast<const half8*>(
                WrP + (((size_t)(p * 32 + q * 8 + w) * 8 + kt) * 512 + l * 8));

    float b_r[4], wk_r[4][3];
#pragma unroll
    for (int q = 0; q < 4; ++q) {
        int col = q * 256 + p * 128 + w * 16 + n;
        b_r[q] = bias[col];
#pragma unroll
        for (int f = 0; f < 3; ++f) wk_r[q][f] = Wk[f * 1024 + col];
    }
    float wd_r[4][3];                     // head: lane l covers units 4l..4l+3
#pragma unroll
    for (int j = 0; j < 4; ++j)
#pragma unroll
        for (int f = 0; f < 3; ++f) wd_r[j][f] = Wd[(4 * l + j) * 3 + f];
    const float bd0 = bd[0], bd1 = bd[1], bd2 = bd[2];

    float cst0[4] = {0.f, 0.f, 0.f, 0.f};
    float cst1[4] = {0.f, 0.f, 0.f, 0.f};
    const int hloc = (w >> 1) * 512 + ((2 * w + (n >> 3)) & 3) * 128
                   + row0 * 8 + (n & 7);
    const int hpos = p * 2048 + hloc;     // own h position in hf[G][par]

    const u64 MSK = 0x0000FFFF0000FFFFull;

    __syncthreads();

#define STEP_GROUP(G, GID, CST)                                                  \
    do {                                                                         \
        const int par_rd = (t - 1) & 1;                                          \
        /* acquire h_{t-1}: one bulk tagged load, predicated backstop */         \
        if (t > 0) {                                                             \
            const u64* src = reinterpret_cast<const u64*>(                       \
                hexT + (((size_t)par_rd * 64 + (GID)) * 2 + pp) * 2048) + tid*2; \
            const u64 tg2 = (u64)(u32)(t - 1) * 0x0000000100000001ull;           \
            u64 w0 = __hip_atomic_load(src + 0, __ATOMIC_RELAXED, __HIP_MEMORY_SCOPE_AGENT); \
            u64 w1 = __hip_atomic_load(src + 1, __ATOMIC_RELAXED, __HIP_MEMORY_SCOPE_AGENT); \
            while (((w0 & MSK) != tg2) || ((w1 & MSK) != tg2)) {                 \
                __builtin_amdgcn_s_sleep(4);                                     \
                w0 = __hip_atomic_load(src + 0, __ATOMIC_RELAXED, __HIP_MEMORY_SCOPE_AGENT); \
                w1 = __hip_atomic_load(src + 1, __ATOMIC_RELAXED, __HIP_MEMORY_SCOPE_AGENT); \
            }                                                                    \
            u64 hv = ((w0 >> 16) & 0xFFFFull) | ((w0 >> 48) << 16)               \
                   | (((w1 >> 16) & 0xFFFFull) << 32) | ((w1 >> 48) << 48);      \
            reinterpret_cast<u64*>(&hf[G][par_rd][pp * 2048])[tid] = hv;         \
            __syncthreads();              /* B1: peer half + own half ordered */ \
        }                                                                        \
        /* head (t>=128): pred from h_{t-1} */                                   \
        if (t >= TIN) {                                                          \
            const int s = t - TIN;                                               \
            _Pragma("unroll")                                                    \
            for (int rr = 0; rr < 2; ++rr) {                                     \
                int row = 2 * w + rr;                                            \
                const _Float16* hb = &hf[G][par_rd][(l >> 3) * 512               \
                                   + ((l >> 1) & 3) * 128 + row * 8 + 4 * (l & 1)]; \
                float p0 = 0.f, p1 = 0.f, p2 = 0.f;                              \
                _Pragma("unroll")                                                \
                for (int j = 0; j < 4; ++j) {                                    \
                    float hj = (float)hb[j];                                     \
                    p0 += hj * wd_r[j][0];                                       \
                    p1 += hj * wd_r[j][1];                                       \
                    p2 += hj * wd_r[j][2];                                       \
                }                                                                \
                _Pragma("unroll")                                                \
                for (int o = 32; o > 0; o >>= 1) {                               \
                    p0 += __shfl_xor(p0, o);                                     \
                    p1 += __shfl_xor(p1, o);                                     \
                    p2 += __shfl_xor(p2, o);                                     \
                }                                                                \
                if (l == 0) {                                                    \
                    p0 += bd0; p1 += bd1; p2 += bd2;                             \
                    pb[G][row][0] = p0; pb[G][row][1] = p1; pb[G][row][2] = p2;  \
                    if (p == 0) {                                                \
                        float* op = out + ((size_t)((GID) * 16 + row) * OSTEPS + s) * 3; \
                        op[0] = p0; op[1] = p1; op[2] = p2;                      \
                    }                                                            \
                }                                                                \
            }                                                                    \
            __syncthreads();              /* B2: pred ready */                   \
        }                                                                        \
        /* cell step (skip at t==LASTT) */                                       \
        if (t < LASTT) {                                                         \
            float xv[4][3];                                                      \
            _Pragma("unroll")                                                    \
            for (int r = 0; r < 4; ++r) {                                        \
                int row = row0 + r;                                              \
                if (t >= TIN) {                                                  \
                    xv[r][0] = pb[G][row][0];                                    \
                    xv[r][1] = pb[G][row][1];                                    \
                    xv[r][2] = pb[G][row][2];                                    \
                } else {                                                         \
                    const float* xp = &xs[G][(row * TIN + t) * 3];               \
                    xv[r][0] = xp[0]; xv[r][1] = xp[1]; xv[r][2] = xp[2];        \
                }                                                                \
            }                                                                    \
            f32x4 acc[4];                                                        \
            _Pragma("unroll")                                                    \
            for (int q = 0; q < 4; ++q)                                          \
                _Pragma("unroll")                                                \
                for (int r = 0; r < 4; ++r)                                      \
                    acc[q][r] = b_r[q] + xv[r][0] * wk_r[q][0]                   \
                              + xv[r][1] * wk_r[q][1] + xv[r][2] * wk_r[q][2];   \
            if (t > 0) {                                                         \
                const int par_rd2 = (t - 1) & 1;                                 \
                _Pragma("unroll")                                                \
                for (int kt = 0; kt < 8; ++kt) {                                 \
                    half8 a = *reinterpret_cast<const half8*>(                   \
                        &hf[G][par_rd2][kt * 512 + l * 8]);                      \
                    _Pragma("unroll")                                            \
                    for (int q = 0; q < 4; ++q)                                  \
                        acc[q] = __builtin_amdgcn_mfma_f32_16x16x32_f16(         \
                            a, bfr[q][kt], acc[q], 0, 0, 0);                     \
                }                                                                \
            }                                                                    \
            const int par_wr = t & 1;                                            \
            u32* wdst = hexT + (((size_t)par_wr * 64 + (GID)) * 2 + p) * 2048 + hloc; \
            _Pragma("unroll")                                                    \
            for (int r = 0; r < 4; ++r) {                                        \
                float iv = sigm(acc[0][r]);                                      \
                float fv = sigm(acc[1][r]);                                      \
                float gv = tanh_f(acc[2][r]);                                    \
                float ov = sigm(acc[3][r]);                                      \
                float cc = fv * CST[r] + iv * gv;                                \
                CST[r] = cc;                                                     \
                _Float16 hh = (_Float16)(ov * tanh_f(cc));                       \
                u32 tw = ((u32)__builtin_bit_cast(unsigned short, hh) << 16) | (u32)t; \
                __hip_atomic_store(wdst + r * 8, tw, __ATOMIC_RELAXED,           \
                                   __HIP_MEMORY_SCOPE_AGENT);                    \
                hf[G][par_wr][hpos + r * 8] = hh;                                \
            }                                                                    \
        }                                                                        \
    } while (0)

    for (int t = 0; t <= LASTT; ++t) {
        STEP_GROUP(0, g0, cst0);
        STEP_GROUP(1, g1, cst1);
        if (t == LASTT) break;
    }
#undef STEP_GROUP
}

extern "C" void kernel_launch(void* const* d_in, const int* in_sizes, int n_in,
                              void* d_out, int out_size, void* d_ws, size_t ws_size,
                              hipStream_t stream)
{
    const float* x  = (const float*)d_in[0];
    const float* Wk = (const float*)d_in[1];
    const float* Wr = (const float*)d_in[2];
    const float* b  = (const float*)d_in[3];
    const float* Wd = (const float*)d_in[4];
    const float* bd = (const float*)d_in[5];
    float* out = (float*)d_out;

    // d_ws: [0,512K) WrP | [512K, 512K+2M) tagged hex
    _Float16* WrP  = (_Float16*)d_ws;
    u32*      hexT = (u32*)((char*)d_ws + 524288);

    hipMemsetAsync(hexT, 0xFF, 2097152, stream);    // tag 0xFFFF: never matches
    pack_wr<<<64, 512, 0, stream>>>(Wr, WrP);
    lstm_pair<<<64, 512, 0, stream>>>(x, Wk, b, Wd, bd, WrP, hexT, out);
}